// Round 8
// baseline (25.525 us; speedup 1.0000x reference)
//
#include <hip/hip_runtime.h>
#include <math.h>

constexpr int NPTS = 1024;
constexpr int WPB = 4;   // waves (= batches) per block

struct F3 { float x, y, z; };   // 12-byte point -> dense dwordx3 loads

// fast HW approximations (v_rcp_f32 / v_rsq_f32 / v_sqrt_f32, ~1ulp)
__device__ __forceinline__ float frcp(float x)  { return __builtin_amdgcn_rcpf(x); }
__device__ __forceinline__ float frsq(float x)  { return __builtin_amdgcn_rsqf(x); }
__device__ __forceinline__ float fsqrt(float x) { return __builtin_amdgcn_sqrtf(x); }

// 3x3 Kabsch solve from the 15 reduced sums; writes R (9) + t (3) for batch b
__device__ __forceinline__ void svd_solve(const float* __restrict__ r,
                                          float* __restrict__ out,
                                          int b, int nbatch)
{
    const float invN = 1.0f / (float)NPTS;
    float mus[3] = {r[0] * invN, r[1] * invN, r[2] * invN};
    float mut[3] = {r[3] * invN, r[4] * invN, r[5] * invN};

    float H[3][3];
#pragma unroll
    for (int i = 0; i < 3; ++i)
#pragma unroll
        for (int j = 0; j < 3; ++j)
            H[i][j] = r[6 + i * 3 + j] - (float)NPTS * mus[i] * mut[j];

    // A = H^T H (symmetric PSD)
    float A[3][3];
#pragma unroll
    for (int i = 0; i < 3; ++i)
#pragma unroll
        for (int j = 0; j < 3; ++j)
            A[i][j] = H[0][i] * H[0][j] + H[1][i] * H[1][j] + H[2][i] * H[2][j];

    // cyclic Jacobi with HW-fast rcp/rsq/sqrt (short dependent chain)
    float V[3][3] = {{1.f, 0.f, 0.f}, {0.f, 1.f, 0.f}, {0.f, 0.f, 1.f}};
    auto rot = [&](int p, int q) {
        float apq = A[p][q];
        float diff = A[q][q] - A[p][p];
        float theta = diff * frcp(2.0f * apq);
        float t = copysignf(frcp(fabsf(theta) + fsqrt(fmaf(theta, theta, 1.0f))), theta);
        t = (fabsf(apq) < 1e-20f) ? 0.0f : t;   // apq==0 -> identity rotation
        float c = frsq(fmaf(t, t, 1.0f));
        float s = t * c;
#pragma unroll
        for (int k = 0; k < 3; ++k) {
            float akp = A[k][p], akq = A[k][q];
            A[k][p] = c * akp - s * akq;
            A[k][q] = s * akp + c * akq;
        }
#pragma unroll
        for (int k = 0; k < 3; ++k) {
            float apk = A[p][k], aqk = A[q][k];
            A[p][k] = c * apk - s * aqk;
            A[q][k] = s * apk + c * aqk;
        }
#pragma unroll
        for (int k = 0; k < 3; ++k) {
            float vkp = V[k][p], vkq = V[k][q];
            V[k][p] = c * vkp - s * vkq;
            V[k][q] = s * vkp + c * vkq;
        }
    };
#pragma unroll
    for (int sweep = 0; sweep < 4; ++sweep) {
        rot(0, 1);
        rot(0, 2);
        rot(1, 2);
    }

    // branchless descending sort of eigenpairs
    float l0 = A[0][0], l1 = A[1][1], l2 = A[2][2];
    float e0[3] = {V[0][0], V[1][0], V[2][0]};
    float e1[3] = {V[0][1], V[1][1], V[2][1]};
    float e2[3] = {V[0][2], V[1][2], V[2][2]};
    auto cswap = [](float& la, float* va, float& lb, float* vb) {
        bool sw = lb > la;
        float tl = sw ? lb : la;
        lb = sw ? la : lb;
        la = tl;
#pragma unroll
        for (int k = 0; k < 3; ++k) {
            float tv2 = sw ? vb[k] : va[k];
            vb[k] = sw ? va[k] : vb[k];
            va[k] = tv2;
        }
    };
    cswap(l0, e0, l1, e1);
    cswap(l0, e0, l2, e2);
    cswap(l1, e1, l2, e2);

    float *v1 = e0, *v2 = e1, *v3 = e2;

    // u1 = norm(H v1); u2 = GramSchmidt(H v2); u3 = u1 x u2  (det U = +1)
    float u1[3], u2[3], u3[3], hv[3];
    hv[0] = H[0][0]*v1[0] + H[0][1]*v1[1] + H[0][2]*v1[2];
    hv[1] = H[1][0]*v1[0] + H[1][1]*v1[1] + H[1][2]*v1[2];
    hv[2] = H[2][0]*v1[0] + H[2][1]*v1[1] + H[2][2]*v1[2];
    {
        float n = frsq(fmaf(hv[0], hv[0], fmaf(hv[1], hv[1], hv[2]*hv[2])) + 1e-30f);
        u1[0] = hv[0] * n; u1[1] = hv[1] * n; u1[2] = hv[2] * n;
    }
    hv[0] = H[0][0]*v2[0] + H[0][1]*v2[1] + H[0][2]*v2[2];
    hv[1] = H[1][0]*v2[0] + H[1][1]*v2[1] + H[1][2]*v2[2];
    hv[2] = H[2][0]*v2[0] + H[2][1]*v2[1] + H[2][2]*v2[2];
    {
        float d = u1[0]*hv[0] + u1[1]*hv[1] + u1[2]*hv[2];
        hv[0] -= d * u1[0]; hv[1] -= d * u1[1]; hv[2] -= d * u1[2];
        float n = frsq(fmaf(hv[0], hv[0], fmaf(hv[1], hv[1], hv[2]*hv[2])) + 1e-30f);
        u2[0] = hv[0] * n; u2[1] = hv[1] * n; u2[2] = hv[2] * n;
    }
    u3[0] = u1[1]*u2[2] - u1[2]*u2[1];
    u3[1] = u1[2]*u2[0] - u1[0]*u2[2];
    u3[2] = u1[0]*u2[1] - u1[1]*u2[0];

    // R = v1 u1^T + v2 u2^T + det(V) * v3 u3^T
    float cx = v1[1]*v2[2] - v1[2]*v2[1];
    float cy = v1[2]*v2[0] - v1[0]*v2[2];
    float cz = v1[0]*v2[1] - v1[1]*v2[0];
    float detV = cx * v3[0] + cy * v3[1] + cz * v3[2];
    float d3 = (detV < 0.f) ? -1.f : 1.f;

    float R[3][3];
#pragma unroll
    for (int i = 0; i < 3; ++i)
#pragma unroll
        for (int j = 0; j < 3; ++j)
            R[i][j] = v1[i]*u1[j] + v2[i]*u2[j] + d3 * v3[i]*u3[j];

    float tvec[3];
#pragma unroll
    for (int i = 0; i < 3; ++i)
        tvec[i] = mut[i] - (R[i][0]*mus[0] + R[i][1]*mus[1] + R[i][2]*mus[2]);

    float* Rout = out + (size_t)b * 9;
#pragma unroll
    for (int i = 0; i < 3; ++i)
#pragma unroll
        for (int j = 0; j < 3; ++j)
            Rout[i * 3 + j] = R[i][j];
    float* tout = out + (size_t)nbatch * 9 + (size_t)b * 3;
#pragma unroll
    for (int i = 0; i < 3; ++i) tout[i] = tvec[i];
}

// Fused: wave-per-batch streaming reduce; block-local LDS handoff; wave 0's
// lanes 0..3 run the block's 4 SVDs in parallel (one exec-masked chain/block).
__global__ __launch_bounds__(256, 4) void kabsch_fused(
    const float* __restrict__ src, const float* __restrict__ tgt,
    float* __restrict__ out, int nbatch)
{
    const int wave = threadIdx.x >> 6;
    const int lane = threadIdx.x & 63;
    const int b = blockIdx.x * WPB + wave;

    float acc[15];
#pragma unroll
    for (int i = 0; i < 15; ++i) acc[i] = 0.f;

    if (b < nbatch) {
        const size_t base = (size_t)b * (NPTS * 3);
        const F3* __restrict__ ps = (const F3*)(src + base);
        const F3* __restrict__ pt = (const F3*)(tgt + base);
#pragma unroll
        for (int k = 0; k < 16; ++k) {
            const int p = k * 64 + lane;
            F3 s = ps[p];
            F3 t = pt[p];
            acc[0] += s.x; acc[1] += s.y; acc[2] += s.z;
            acc[3] += t.x; acc[4] += t.y; acc[5] += t.z;
            acc[6]  += s.x * t.x; acc[7]  += s.x * t.y; acc[8]  += s.x * t.z;
            acc[9]  += s.y * t.x; acc[10] += s.y * t.y; acc[11] += s.y * t.z;
            acc[12] += s.z * t.x; acc[13] += s.z * t.y; acc[14] += s.z * t.z;
        }
    }

    // wave butterfly reduce (valid on lane 0)
#pragma unroll
    for (int off = 32; off >= 1; off >>= 1) {
#pragma unroll
        for (int i = 0; i < 15; ++i)
            acc[i] += __shfl_down(acc[i], off, 64);
    }

    // block-local handoff: 15 sums per wave -> LDS
    __shared__ float smem[WPB][16];
    if (b < nbatch && lane == 0) {
#pragma unroll
        for (int i = 0; i < 15; ++i) smem[wave][i] = acc[i];
    }
    __syncthreads();

    // wave 0, lanes 0..3: one SVD per batch of this block, in parallel
    if (wave == 0 && lane < WPB) {
        const int sb = blockIdx.x * WPB + lane;
        if (sb < nbatch) {
            float r[15];
#pragma unroll
            for (int i = 0; i < 15; ++i) r[i] = smem[lane][i];
            svd_solve(r, out, sb, nbatch);
        }
    }
}

extern "C" void kernel_launch(void* const* d_in, const int* in_sizes, int n_in,
                              void* d_out, int out_size, void* d_ws, size_t ws_size,
                              hipStream_t stream) {
    const float* src = (const float*)d_in[0];
    const float* tgt = (const float*)d_in[1];
    float* out = (float*)d_out;
    const int nbatch = in_sizes[0] / (NPTS * 3);

    const int nblocks = (nbatch + WPB - 1) / WPB;
    kabsch_fused<<<nblocks, 256, 0, stream>>>(src, tgt, out, nbatch);
}